// Round 2
// baseline (2114.593 us; speedup 1.0000x reference)
//
#include <hip/hip_runtime.h>
#include <hip/hip_bf16.h>

// Problem constants (from reference)
#define SEQ 2048
#define DMODEL 1024
#define NHEAD 16
#define HDIM 64
#define DPOS 64
#define BATCH 2

constexpr float EVENT_HORIZON = 1e-6f;
constexpr float MAX_FORCE = 50.0f;
constexpr float CURV = 0.15f;

// ---------------------------------------------------------------------------
// Kernel 1: masses[b,h,s] = softplus( dot(x[b,s,h*64:+64], W_mass[h,:]) )
// layout: masses[(b*NHEAD+h)*SEQ + s]
// ---------------------------------------------------------------------------
__global__ __launch_bounds__(256) void masses_kernel(
    const float* __restrict__ x,
    const float* __restrict__ Wm,
    float* __restrict__ masses) {
  int n = blockIdx.x * blockDim.x + threadIdx.x;  // n = (b*NHEAD+h)*SEQ + s
  if (n >= BATCH * NHEAD * SEQ) return;
  int s  = n & (SEQ - 1);
  int bh = n >> 11;           // n / SEQ
  int h  = bh & (NHEAD - 1);
  int b  = bh >> 4;
  const float* xp = x + ((size_t)(b * SEQ + s)) * DMODEL + h * HDIM;
  const float* wp = Wm + h * HDIM;
  float acc = 0.f;
#pragma unroll
  for (int d = 0; d < HDIM; ++d)
    acc += xp[d] * wp[d];
  // softplus(acc) = log(1+exp(acc)); guard overflow
  float m = (acc > 20.f) ? acc : log1pf(expf(acc));
  masses[n] = m;
}

// ---------------------------------------------------------------------------
// Kernel 2: invd[i,j] = 1 / max( d2*(1+0.15*cos(sqrt(d2+eps))), eps )
// d2 = ||pos_i - pos_j||^2 over 64 dims
// ---------------------------------------------------------------------------
__global__ __launch_bounds__(256) void invdist_kernel(
    const float* __restrict__ pos,
    float* __restrict__ invd) {
  int idx = blockIdx.x * blockDim.x + threadIdx.x;  // i*SEQ + j
  int i = idx >> 11;
  int j = idx & (SEQ - 1);
  const float* pi = pos + (size_t)i * DPOS;
  const float* pj = pos + (size_t)j * DPOS;
  float d = 0.f;
#pragma unroll
  for (int p = 0; p < DPOS; ++p) {
    float t = pi[p] - pj[p];
    d += t * t;
  }
  float dn = sqrtf(d + EVENT_HORIZON);
  float w = d * (1.f + CURV * cosf(dn));
  w = fmaxf(w, EVENT_HORIZON);
  invd[idx] = 1.0f / w;
}

// ---------------------------------------------------------------------------
// Kernel 3: attention. One wave per output row (b,h,i).
// Scores are in [0, 50] (masses>0, G>0, invd>0, clamp 50), so softmax without
// max-subtraction is numerically safe in fp32 (sum exp <= 2048*e^50 ~ 1e25).
// lane = head dim d. attnout[(b*SEQ+i)*DMODEL + h*HDIM + d] (fp32)
// ---------------------------------------------------------------------------
__global__ __launch_bounds__(256) void attn_kernel(
    const float* __restrict__ x,
    const float* __restrict__ masses,
    const float* __restrict__ invd,
    const float* __restrict__ G,
    float* __restrict__ attnout) {
  int r    = blockIdx.x * 4 + (threadIdx.x >> 6);  // row id = (b*NHEAD+h)*SEQ + i
  int lane = threadIdx.x & 63;
  int i  = r & (SEQ - 1);
  int bh = r >> 11;
  int h  = bh & (NHEAD - 1);
  int b  = bh >> 4;

  float gabs = fabsf(G[h]);
  const float* mrow   = masses + (size_t)bh * SEQ;
  float cm            = gabs * mrow[i];
  const float* invrow = invd + (size_t)i * SEQ;
  const float* V = x + (size_t)b * SEQ * DMODEL + h * HDIM;  // V[j][d] at V[j*DMODEL+d]

  float acc = 0.f;
  float sum = 0.f;
  for (int j0 = 0; j0 < SEQ; j0 += 64) {
    // each lane computes one score in this 64-wide stripe
    float sc = cm * mrow[j0 + lane] * invrow[j0 + lane];
    sc = fminf(sc, MAX_FORCE);
    float e = __expf(sc);
    sum += e;
    // broadcast each e_j across the wave; lane accumulates dim d=lane
#pragma unroll 8
    for (int jj = 0; jj < 64; ++jj) {
      float ej = __shfl(e, jj, 64);
      acc += ej * V[(size_t)(j0 + jj) * DMODEL + lane];
    }
  }
  // wave-reduce sum of exps
#pragma unroll
  for (int off = 32; off; off >>= 1) sum += __shfl_xor(sum, off, 64);

  attnout[(size_t)(b * SEQ + i) * DMODEL + h * HDIM + lane] = acc / sum;
}

// ---------------------------------------------------------------------------
// Kernel 4: out = attnout @ W_out^T  (NT gemm, fp32 accum, fp32 store)
// C[m][n] = sum_k A[m][k] * W[n][k];  M=4096, N=K=1024
// ---------------------------------------------------------------------------
__global__ __launch_bounds__(256) void out_gemm(
    const float* __restrict__ A,
    const float* __restrict__ W,
    float* __restrict__ C) {
  __shared__ float As[16][17];
  __shared__ float Bs[16][17];
  int tx = threadIdx.x & 15;   // n within tile (also k for loads)
  int ty = threadIdx.x >> 4;   // m within tile (also n for B loads)
  int m0 = blockIdx.y * 16;
  int n0 = blockIdx.x * 16;
  float acc = 0.f;
  for (int k0 = 0; k0 < DMODEL; k0 += 16) {
    As[ty][tx] = A[(size_t)(m0 + ty) * DMODEL + k0 + tx];
    Bs[ty][tx] = W[(size_t)(n0 + ty) * DMODEL + k0 + tx];
    __syncthreads();
#pragma unroll
    for (int k = 0; k < 16; ++k) acc += As[ty][k] * Bs[tx][k];
    __syncthreads();
  }
  C[(size_t)(m0 + ty) * DMODEL + n0 + tx] = acc;
}

// ---------------------------------------------------------------------------
extern "C" void kernel_launch(void* const* d_in, const int* in_sizes, int n_in,
                              void* d_out, int out_size, void* d_ws, size_t ws_size,
                              hipStream_t stream) {
  const float* x    = (const float*)d_in[0];  // [B,S,D]
  const float* pos  = (const float*)d_in[1];  // [S,P]
  const float* Wm   = (const float*)d_in[2];  // [H,hd]
  const float* G    = (const float*)d_in[3];  // [H]
  const float* Wout = (const float*)d_in[4];  // [D,D]
  float* out = (float*)d_out;

  float* ws      = (float*)d_ws;
  float* masses  = ws;                         // 65536 floats
  float* invd    = ws + 65536;                 // 4,194,304 floats
  float* attnout = invd + (size_t)SEQ * SEQ;   // 4,194,304 floats

  masses_kernel<<<(BATCH * NHEAD * SEQ) / 256, 256, 0, stream>>>(x, Wm, masses);
  invdist_kernel<<<(SEQ * SEQ) / 256, 256, 0, stream>>>(pos, invd);
  attn_kernel<<<(BATCH * NHEAD * SEQ) / 4, 256, 0, stream>>>(x, masses, invd, G, attnout);
  dim3 ggrid(DMODEL / 16, (BATCH * SEQ) / 16);
  out_gemm<<<ggrid, 256, 0, stream>>>(attnout, Wout, out);
}

// Round 3
// 366.557 us; speedup vs baseline: 5.7688x; 5.7688x over previous
//
#include <hip/hip_runtime.h>
#include <hip/hip_bf16.h>

#define SEQ 2048
#define DMODEL 1024
#define NHEAD 16
#define HDIM 64
#define DPOS 64
#define BATCH 2

constexpr float EVENT_HORIZON = 1e-6f;
constexpr float MAX_FORCE = 50.0f;
constexpr float CURV = 0.15f;

typedef __attribute__((ext_vector_type(8))) short frag8;    // 8 bf16 (A/B operand)
typedef __attribute__((ext_vector_type(4))) float frag4f;   // 4 fp32 (C/D)

__device__ inline short bfbits(float f) {
  __hip_bfloat16 h = __float2bfloat16(f);
  return *reinterpret_cast<short*>(&h);
}

// ---------------------------------------------------------------------------
// Kernel 1: masses[bh][s] = softplus( dot(x[b,s,h*64:+64], W_mass[h,:]) )
// ---------------------------------------------------------------------------
__global__ __launch_bounds__(256) void masses_kernel(
    const float* __restrict__ x, const float* __restrict__ Wm,
    float* __restrict__ masses) {
  int n = blockIdx.x * blockDim.x + threadIdx.x;
  if (n >= BATCH * NHEAD * SEQ) return;
  int s  = n & (SEQ - 1);
  int bh = n >> 11;
  int h  = bh & (NHEAD - 1);
  int b  = bh >> 4;
  const float* xp = x + ((size_t)(b * SEQ + s)) * DMODEL + h * HDIM;
  const float* wp = Wm + h * HDIM;
  float acc = 0.f;
#pragma unroll
  for (int d = 0; d < HDIM; ++d) acc += xp[d] * wp[d];
  masses[n] = (acc > 20.f) ? acc : log1pf(expf(acc));
}

// ---------------------------------------------------------------------------
// Kernel 2: invd[i][j] = 1 / max( d2*(1+0.15*cos(sqrt(d2+eps))), eps )
// ---------------------------------------------------------------------------
__global__ __launch_bounds__(256) void invdist_kernel(
    const float* __restrict__ pos, float* __restrict__ invd) {
  int idx = blockIdx.x * blockDim.x + threadIdx.x;
  int i = idx >> 11;
  int j = idx & (SEQ - 1);
  const float4* pi = (const float4*)(pos + (size_t)i * DPOS);
  const float4* pj = (const float4*)(pos + (size_t)j * DPOS);
  float d = 0.f;
#pragma unroll
  for (int p = 0; p < DPOS / 4; ++p) {
    float4 a = pi[p], b = pj[p];
    float t0 = a.x - b.x, t1 = a.y - b.y, t2 = a.z - b.z, t3 = a.w - b.w;
    d += t0 * t0 + t1 * t1 + t2 * t2 + t3 * t3;
  }
  float dn = sqrtf(d + EVENT_HORIZON);
  float w = d * (1.f + CURV * cosf(dn));
  invd[idx] = 1.0f / fmaxf(w, EVENT_HORIZON);
}

// ---------------------------------------------------------------------------
// Kernel 3: fused gravitational attention, MFMA PV.
// Block = 256 thr = 4 waves. Block covers (bh, 128 i-rows); wave covers 32 i.
// P computed on-the-fly into A-frags; V staged transposed into LDS as bf16.
// attnout is bf16 [B*S][DMODEL] (feeds MFMA out-proj).
// Scores in (0,50] -> softmax without max-subtraction safe in fp32.
// Denominator accumulates bf16-rounded exps (consistent with numerator).
// ---------------------------------------------------------------------------
__global__ __launch_bounds__(256, 2) void attn_mfma_kernel(
    const float* __restrict__ x, const float* __restrict__ masses,
    const float* __restrict__ invd, const float* __restrict__ G,
    __hip_bfloat16* __restrict__ attnout) {
  // Vt[d][jlocal], row stride 40 bf16 (80 B: 16B-aligned rows, breaks pow2)
  __shared__ __hip_bfloat16 Vt[64 * 40];

  int bh = blockIdx.x;
  int h = bh & (NHEAD - 1);
  int b = bh >> 4;
  int i0 = blockIdx.y * 128;
  int t = threadIdx.x;
  int w = t >> 6, lane = t & 63;
  int l15 = lane & 15, quad = lane >> 4;

  float gabs = fabsf(G[h]);
  const float* mrow = masses + (size_t)bh * SEQ;
  const float* xv = x + (size_t)b * SEQ * DMODEL + h * HDIM;  // V[j][d] = xv[j*1024+d]

  int iw = i0 + w * 32;  // this wave's first row
  float cm0 = gabs * mrow[iw + l15];         // row scalar for mt=0 (i = iw+l15)
  float cm1 = gabs * mrow[iw + 16 + l15];    // mt=1
  const float* ir0 = invd + (size_t)(iw + l15) * SEQ;
  const float* ir1 = invd + (size_t)(iw + 16 + l15) * SEQ;

  // staging role: thread t loads d = t&63, j-block = t>>6 (8 consecutive j)
  int sd = t & 63;
  int sjb = t >> 6;
  const float* xcol = xv + sd;

  frag4f acc[2][4];
#pragma unroll
  for (int mt = 0; mt < 2; ++mt)
#pragma unroll
    for (int nt = 0; nt < 4; ++nt) acc[mt][nt] = (frag4f)0.f;
  float sum0 = 0.f, sum1 = 0.f;

  for (int j0 = 0; j0 < SEQ; j0 += 32) {
    // ---- stage V chunk (transposed, fp32->bf16) ----
    float vv[8];
#pragma unroll
    for (int jj = 0; jj < 8; ++jj)
      vv[jj] = xcol[(size_t)(j0 + sjb * 8 + jj) * DMODEL];
    frag8 vb;
#pragma unroll
    for (int jj = 0; jj < 8; ++jj) vb[jj] = bfbits(vv[jj]);
    __syncthreads();  // previous chunk's reads done
    *(frag8*)(&Vt[sd * 40 + sjb * 8]) = vb;
    __syncthreads();  // writes visible

    // ---- A-frags: P = bf16(exp(min(cm * m_j * invd, 50))) ----
    int jb = j0 + quad * 8;
    float4 mja = *(const float4*)(mrow + jb);
    float4 mjb = *(const float4*)(mrow + jb + 4);
    float mj[8] = {mja.x, mja.y, mja.z, mja.w, mjb.x, mjb.y, mjb.z, mjb.w};
    float4 iva = *(const float4*)(ir0 + jb);
    float4 ivb = *(const float4*)(ir0 + jb + 4);
    float iv0[8] = {iva.x, iva.y, iva.z, iva.w, ivb.x, ivb.y, ivb.z, ivb.w};
    float4 jva = *(const float4*)(ir1 + jb);
    float4 jvb = *(const float4*)(ir1 + jb + 4);
    float iv1[8] = {jva.x, jva.y, jva.z, jva.w, jvb.x, jvb.y, jvb.z, jvb.w};

    frag8 A0, A1;
#pragma unroll
    for (int jj = 0; jj < 8; ++jj) {
      float e0 = __expf(fminf(cm0 * mj[jj] * iv0[jj], MAX_FORCE));
      short r0 = bfbits(e0);
      __hip_bfloat16 h0 = *reinterpret_cast<__hip_bfloat16*>(&r0);
      sum0 += __bfloat162float(h0);
      A0[jj] = r0;
      float e1 = __expf(fminf(cm1 * mj[jj] * iv1[jj], MAX_FORCE));
      short r1 = bfbits(e1);
      __hip_bfloat16 h1 = *reinterpret_cast<__hip_bfloat16*>(&r1);
      sum1 += __bfloat162float(h1);
      A1[jj] = r1;
    }

    // ---- B-frags from LDS + MFMA ----
    frag8 Bf[4];
#pragma unroll
    for (int nt = 0; nt < 4; ++nt)
      Bf[nt] = *(const frag8*)(&Vt[(nt * 16 + l15) * 40 + quad * 8]);
#pragma unroll
    for (int nt = 0; nt < 4; ++nt) {
      acc[0][nt] = __builtin_amdgcn_mfma_f32_16x16x32_bf16(A0, Bf[nt], acc[0][nt], 0, 0, 0);
      acc[1][nt] = __builtin_amdgcn_mfma_f32_16x16x32_bf16(A1, Bf[nt], acc[1][nt], 0, 0, 0);
    }
  }

  // ---- normalize + store ----
  sum0 += __shfl_xor(sum0, 16, 64);
  sum0 += __shfl_xor(sum0, 32, 64);
  sum1 += __shfl_xor(sum1, 16, 64);
  sum1 += __shfl_xor(sum1, 32, 64);
  // lane L now holds row-sum for row (L&15) of its mt group

#pragma unroll
  for (int reg = 0; reg < 4; ++reg) {
    int r = quad * 4 + reg;            // C/D row within 16x16 tile
    float s0 = 1.f / __shfl(sum0, r);
    float s1 = 1.f / __shfl(sum1, r);
#pragma unroll
    for (int nt = 0; nt < 4; ++nt) {
      int dcol = h * HDIM + nt * 16 + l15;
      attnout[(size_t)(b * SEQ + iw + r) * DMODEL + dcol] =
          __float2bfloat16(acc[0][nt][reg] * s0);
      attnout[(size_t)(b * SEQ + iw + 16 + r) * DMODEL + dcol] =
          __float2bfloat16(acc[1][nt][reg] * s1);
    }
  }
}

// ---------------------------------------------------------------------------
// Kernel 4: out = attnout @ W_out^T via bf16 MFMA. C[m][n] = sum_k A[m][k]W[n][k]
// M=4096, N=K=1024. Tile 128(M) x 64(N), K-chunk 32. 4 waves, wave = 64m x 32n.
// ---------------------------------------------------------------------------
__global__ __launch_bounds__(256, 2) void out_gemm_mfma(
    const __hip_bfloat16* __restrict__ Ag, const float* __restrict__ Wg,
    float* __restrict__ C) {
  __shared__ __hip_bfloat16 As[128 * 40];  // [m][k] stride 40
  __shared__ __hip_bfloat16 Bs[64 * 40];   // [n][k] stride 40

  int t = threadIdx.x;
  int w = t >> 6, lane = t & 63;
  int l15 = lane & 15, quad = lane >> 4;
  int m0 = blockIdx.y * 128;
  int n0 = blockIdx.x * 64;
  int mhalf = (w & 1) * 64;
  int nhalf = (w >> 1) * 32;

  // staging roles
  int ar = t >> 1, akb = t & 1;   // A: row 0..127, 16 bf16 each
  int br = t >> 2, bkb = t & 3;   // B: row 0..63, 8 fp32 each

  frag4f acc[4][2];
#pragma unroll
  for (int mt = 0; mt < 4; ++mt)
#pragma unroll
    for (int nt = 0; nt < 2; ++nt) acc[mt][nt] = (frag4f)0.f;

  for (int k0 = 0; k0 < DMODEL; k0 += 32) {
    // load A (bf16): 16 bf16 = two frag8
    const frag8* ap = (const frag8*)(Ag + (size_t)(m0 + ar) * DMODEL + k0 + akb * 16);
    frag8 a0 = ap[0], a1 = ap[1];
    // load B (fp32 -> bf16): 8 floats
    const float4* bp = (const float4*)(Wg + (size_t)(n0 + br) * DMODEL + k0 + bkb * 8);
    float4 b0 = bp[0], b1 = bp[1];
    frag8 bb;
    bb[0] = bfbits(b0.x); bb[1] = bfbits(b0.y); bb[2] = bfbits(b0.z); bb[3] = bfbits(b0.w);
    bb[4] = bfbits(b1.x); bb[5] = bfbits(b1.y); bb[6] = bfbits(b1.z); bb[7] = bfbits(b1.w);

    __syncthreads();
    *(frag8*)(&As[ar * 40 + akb * 16]) = a0;
    *(frag8*)(&As[ar * 40 + akb * 16 + 8]) = a1;
    *(frag8*)(&Bs[br * 40 + bkb * 8]) = bb;
    __syncthreads();

    frag8 Af[4], Bf[2];
#pragma unroll
    for (int mt = 0; mt < 4; ++mt)
      Af[mt] = *(const frag8*)(&As[(mhalf + mt * 16 + l15) * 40 + quad * 8]);
#pragma unroll
    for (int nt = 0; nt < 2; ++nt)
      Bf[nt] = *(const frag8*)(&Bs[(nhalf + nt * 16 + l15) * 40 + quad * 8]);
#pragma unroll
    for (int mt = 0; mt < 4; ++mt)
#pragma unroll
      for (int nt = 0; nt < 2; ++nt)
        acc[mt][nt] = __builtin_amdgcn_mfma_f32_16x16x32_bf16(Af[mt], Bf[nt], acc[mt][nt], 0, 0, 0);
  }

#pragma unroll
  for (int mt = 0; mt < 4; ++mt)
#pragma unroll
    for (int nt = 0; nt < 2; ++nt)
#pragma unroll
      for (int reg = 0; reg < 4; ++reg) {
        int m = m0 + mhalf + mt * 16 + quad * 4 + reg;
        int n = n0 + nhalf + nt * 16 + l15;
        C[(size_t)m * DMODEL + n] = acc[mt][nt][reg];
      }
}

// ---------------------------------------------------------------------------
extern "C" void kernel_launch(void* const* d_in, const int* in_sizes, int n_in,
                              void* d_out, int out_size, void* d_ws, size_t ws_size,
                              hipStream_t stream) {
  const float* x    = (const float*)d_in[0];
  const float* pos  = (const float*)d_in[1];
  const float* Wm   = (const float*)d_in[2];
  const float* G    = (const float*)d_in[3];
  const float* Wout = (const float*)d_in[4];
  float* out = (float*)d_out;

  float* ws = (float*)d_ws;
  float* masses = ws;                                    // 65536 fp32
  float* invd = ws + 65536;                              // 4M fp32
  __hip_bfloat16* attnout = (__hip_bfloat16*)(invd + (size_t)SEQ * SEQ);  // 4M bf16

  masses_kernel<<<(BATCH * NHEAD * SEQ) / 256, 256, 0, stream>>>(x, Wm, masses);
  invdist_kernel<<<(SEQ * SEQ) / 256, 256, 0, stream>>>(pos, invd);
  attn_mfma_kernel<<<dim3(BATCH * NHEAD, SEQ / 128), 256, 0, stream>>>(
      x, masses, invd, G, attnout);
  out_gemm_mfma<<<dim3(DMODEL / 64, (BATCH * SEQ) / 128), 256, 0, stream>>>(
      attnout, Wout, out);
}

// Round 4
// 237.982 us; speedup vs baseline: 8.8855x; 1.5403x over previous
//
#include <hip/hip_runtime.h>
#include <hip/hip_bf16.h>

#define SEQ 2048
#define DMODEL 1024
#define NHEAD 16
#define HDIM 64
#define DPOS 64
#define BATCH 2

constexpr float EVENT_HORIZON = 1e-6f;
constexpr float MAX_FORCE = 50.0f;
constexpr float CURV = 0.15f;

typedef __attribute__((ext_vector_type(8))) short frag8;    // 8 bf16 (A/B operand)
typedef __attribute__((ext_vector_type(4))) float frag4f;   // 4 fp32 (C/D)

__device__ inline short bfbits(float f) {
  __hip_bfloat16 h = __float2bfloat16(f);
  return *reinterpret_cast<short*>(&h);
}

// ---------------------------------------------------------------------------
// Kernel 1: masses[bh][s] = softplus( dot(x[b,s,h*64:+64], W_mass[h,:]) )
// ---------------------------------------------------------------------------
__global__ __launch_bounds__(256) void masses_kernel(
    const float* __restrict__ x, const float* __restrict__ Wm,
    float* __restrict__ masses) {
  int n = blockIdx.x * blockDim.x + threadIdx.x;
  if (n >= BATCH * NHEAD * SEQ) return;
  int s  = n & (SEQ - 1);
  int bh = n >> 11;
  int h  = bh & (NHEAD - 1);
  int b  = bh >> 4;
  const float* xp = x + ((size_t)(b * SEQ + s)) * DMODEL + h * HDIM;
  const float* wp = Wm + h * HDIM;
  float acc = 0.f;
#pragma unroll
  for (int d = 0; d < HDIM; ++d) acc += xp[d] * wp[d];
  masses[n] = (acc > 20.f) ? acc : log1pf(expf(acc));
}

// ---------------------------------------------------------------------------
// Kernel 2 (v2): LDS-tiled distance kernel.
// 64x64 output tile / block; pos tiles staged coalesced into LDS [k][row]
// (row stride 68 floats: 16B-aligned b128 reads, <=2-way bank alias = free).
// Each thread owns a 4(i) x 4(j) register tile; stores are float4-coalesced.
// ---------------------------------------------------------------------------
__global__ __launch_bounds__(256) void invdist_kernel(
    const float* __restrict__ pos, float* __restrict__ invd) {
  __shared__ float Li[64 * 68];
  __shared__ float Lj[64 * 68];
  int t = threadIdx.x;
  int i0 = blockIdx.y * 64, j0 = blockIdx.x * 64;

  // coalesced staging: thread t loads flat float4 #(q*256+t) of each 16KB tile
  int kk = (t & 15) * 4;   // k start
  int rr = t >> 4;         // row base
#pragma unroll
  for (int q = 0; q < 4; ++q) {
    int row = q * 16 + rr;
    float4 a = *(const float4*)(pos + (size_t)(i0 + row) * DPOS + kk);
    float4 b = *(const float4*)(pos + (size_t)(j0 + row) * DPOS + kk);
    Li[(kk + 0) * 68 + row] = a.x; Li[(kk + 1) * 68 + row] = a.y;
    Li[(kk + 2) * 68 + row] = a.z; Li[(kk + 3) * 68 + row] = a.w;
    Lj[(kk + 0) * 68 + row] = b.x; Lj[(kk + 1) * 68 + row] = b.y;
    Lj[(kk + 2) * 68 + row] = b.z; Lj[(kk + 3) * 68 + row] = b.w;
  }
  __syncthreads();

  int ti = (t >> 4) * 4;   // i offset in tile
  int tj = (t & 15) * 4;   // j offset in tile (lane-fast -> coalesced stores)

  float acc[4][4];
#pragma unroll
  for (int a = 0; a < 4; ++a)
#pragma unroll
    for (int b = 0; b < 4; ++b) acc[a][b] = 0.f;

#pragma unroll 8
  for (int k = 0; k < 64; ++k) {
    float4 a = *(const float4*)(&Li[k * 68 + ti]);
    float4 b = *(const float4*)(&Lj[k * 68 + tj]);
    float av[4] = {a.x, a.y, a.z, a.w};
    float bv[4] = {b.x, b.y, b.z, b.w};
#pragma unroll
    for (int mi = 0; mi < 4; ++mi)
#pragma unroll
      for (int mj = 0; mj < 4; ++mj) {
        float d = av[mi] - bv[mj];
        acc[mi][mj] += d * d;
      }
  }

#pragma unroll
  for (int mi = 0; mi < 4; ++mi) {
    float4 o;
    float* op = (float*)&o;
#pragma unroll
    for (int mj = 0; mj < 4; ++mj) {
      float d2 = acc[mi][mj];
      float dn = sqrtf(d2 + EVENT_HORIZON);
      float w = d2 * (1.f + CURV * __cosf(dn));
      op[mj] = 1.0f / fmaxf(w, EVENT_HORIZON);
    }
    *(float4*)(&invd[(size_t)(i0 + ti + mi) * SEQ + j0 + tj]) = o;
  }
}

// ---------------------------------------------------------------------------
// Kernel 3: fused gravitational attention, MFMA PV.
// Block = 256 thr = 4 waves. Block covers (bh, 128 i-rows); wave covers 32 i.
// P computed on-the-fly into A-frags; V staged transposed into LDS as bf16.
// attnout is bf16 [B*S][DMODEL] (feeds MFMA out-proj).
// Scores in (0,50] -> softmax without max-subtraction safe in fp32.
// ---------------------------------------------------------------------------
__global__ __launch_bounds__(256, 2) void attn_mfma_kernel(
    const float* __restrict__ x, const float* __restrict__ masses,
    const float* __restrict__ invd, const float* __restrict__ G,
    __hip_bfloat16* __restrict__ attnout) {
  __shared__ __hip_bfloat16 Vt[64 * 40];

  int bh = blockIdx.x;
  int h = bh & (NHEAD - 1);
  int b = bh >> 4;
  int i0 = blockIdx.y * 128;
  int t = threadIdx.x;
  int w = t >> 6, lane = t & 63;
  int l15 = lane & 15, quad = lane >> 4;

  float gabs = fabsf(G[h]);
  const float* mrow = masses + (size_t)bh * SEQ;
  const float* xv = x + (size_t)b * SEQ * DMODEL + h * HDIM;

  int iw = i0 + w * 32;
  float cm0 = gabs * mrow[iw + l15];
  float cm1 = gabs * mrow[iw + 16 + l15];
  const float* ir0 = invd + (size_t)(iw + l15) * SEQ;
  const float* ir1 = invd + (size_t)(iw + 16 + l15) * SEQ;

  int sd = t & 63;
  int sjb = t >> 6;
  const float* xcol = xv + sd;

  frag4f acc[2][4];
#pragma unroll
  for (int mt = 0; mt < 2; ++mt)
#pragma unroll
    for (int nt = 0; nt < 4; ++nt) acc[mt][nt] = (frag4f)0.f;
  float sum0 = 0.f, sum1 = 0.f;

  for (int j0 = 0; j0 < SEQ; j0 += 32) {
    float vv[8];
#pragma unroll
    for (int jj = 0; jj < 8; ++jj)
      vv[jj] = xcol[(size_t)(j0 + sjb * 8 + jj) * DMODEL];
    frag8 vb;
#pragma unroll
    for (int jj = 0; jj < 8; ++jj) vb[jj] = bfbits(vv[jj]);
    __syncthreads();
    *(frag8*)(&Vt[sd * 40 + sjb * 8]) = vb;
    __syncthreads();

    int jb = j0 + quad * 8;
    float4 mja = *(const float4*)(mrow + jb);
    float4 mjb = *(const float4*)(mrow + jb + 4);
    float mj[8] = {mja.x, mja.y, mja.z, mja.w, mjb.x, mjb.y, mjb.z, mjb.w};
    float4 iva = *(const float4*)(ir0 + jb);
    float4 ivb = *(const float4*)(ir0 + jb + 4);
    float iv0[8] = {iva.x, iva.y, iva.z, iva.w, ivb.x, ivb.y, ivb.z, ivb.w};
    float4 jva = *(const float4*)(ir1 + jb);
    float4 jvb = *(const float4*)(ir1 + jb + 4);
    float iv1[8] = {jva.x, jva.y, jva.z, jva.w, jvb.x, jvb.y, jvb.z, jvb.w};

    frag8 A0, A1;
#pragma unroll
    for (int jj = 0; jj < 8; ++jj) {
      float e0 = __expf(fminf(cm0 * mj[jj] * iv0[jj], MAX_FORCE));
      short r0 = bfbits(e0);
      __hip_bfloat16 h0 = *reinterpret_cast<__hip_bfloat16*>(&r0);
      sum0 += __bfloat162float(h0);
      A0[jj] = r0;
      float e1 = __expf(fminf(cm1 * mj[jj] * iv1[jj], MAX_FORCE));
      short r1 = bfbits(e1);
      __hip_bfloat16 h1 = *reinterpret_cast<__hip_bfloat16*>(&r1);
      sum1 += __bfloat162float(h1);
      A1[jj] = r1;
    }

    frag8 Bf[4];
#pragma unroll
    for (int nt = 0; nt < 4; ++nt)
      Bf[nt] = *(const frag8*)(&Vt[(nt * 16 + l15) * 40 + quad * 8]);
#pragma unroll
    for (int nt = 0; nt < 4; ++nt) {
      acc[0][nt] = __builtin_amdgcn_mfma_f32_16x16x32_bf16(A0, Bf[nt], acc[0][nt], 0, 0, 0);
      acc[1][nt] = __builtin_amdgcn_mfma_f32_16x16x32_bf16(A1, Bf[nt], acc[1][nt], 0, 0, 0);
    }
  }

  sum0 += __shfl_xor(sum0, 16, 64);
  sum0 += __shfl_xor(sum0, 32, 64);
  sum1 += __shfl_xor(sum1, 16, 64);
  sum1 += __shfl_xor(sum1, 32, 64);

#pragma unroll
  for (int reg = 0; reg < 4; ++reg) {
    int r = quad * 4 + reg;
    float s0 = 1.f / __shfl(sum0, r);
    float s1 = 1.f / __shfl(sum1, r);
#pragma unroll
    for (int nt = 0; nt < 4; ++nt) {
      int dcol = h * HDIM + nt * 16 + l15;
      attnout[(size_t)(b * SEQ + iw + r) * DMODEL + dcol] =
          __float2bfloat16(acc[0][nt][reg] * s0);
      attnout[(size_t)(b * SEQ + iw + 16 + r) * DMODEL + dcol] =
          __float2bfloat16(acc[1][nt][reg] * s1);
    }
  }
}

// ---------------------------------------------------------------------------
// Kernel 4: out = attnout @ W_out^T via bf16 MFMA. C[m][n] = sum_k A[m][k]W[n][k]
// ---------------------------------------------------------------------------
__global__ __launch_bounds__(256, 2) void out_gemm_mfma(
    const __hip_bfloat16* __restrict__ Ag, const float* __restrict__ Wg,
    float* __restrict__ C) {
  __shared__ __hip_bfloat16 As[128 * 40];
  __shared__ __hip_bfloat16 Bs[64 * 40];

  int t = threadIdx.x;
  int w = t >> 6, lane = t & 63;
  int l15 = lane & 15, quad = lane >> 4;
  int m0 = blockIdx.y * 128;
  int n0 = blockIdx.x * 64;
  int mhalf = (w & 1) * 64;
  int nhalf = (w >> 1) * 32;

  int ar = t >> 1, akb = t & 1;
  int br = t >> 2, bkb = t & 3;

  frag4f acc[4][2];
#pragma unroll
  for (int mt = 0; mt < 4; ++mt)
#pragma unroll
    for (int nt = 0; nt < 2; ++nt) acc[mt][nt] = (frag4f)0.f;

  for (int k0 = 0; k0 < DMODEL; k0 += 32) {
    const frag8* ap = (const frag8*)(Ag + (size_t)(m0 + ar) * DMODEL + k0 + akb * 16);
    frag8 a0 = ap[0], a1 = ap[1];
    const float4* bp = (const float4*)(Wg + (size_t)(n0 + br) * DMODEL + k0 + bkb * 8);
    float4 b0 = bp[0], b1 = bp[1];
    frag8 bb;
    bb[0] = bfbits(b0.x); bb[1] = bfbits(b0.y); bb[2] = bfbits(b0.z); bb[3] = bfbits(b0.w);
    bb[4] = bfbits(b1.x); bb[5] = bfbits(b1.y); bb[6] = bfbits(b1.z); bb[7] = bfbits(b1.w);

    __syncthreads();
    *(frag8*)(&As[ar * 40 + akb * 16]) = a0;
    *(frag8*)(&As[ar * 40 + akb * 16 + 8]) = a1;
    *(frag8*)(&Bs[br * 40 + bkb * 8]) = bb;
    __syncthreads();

    frag8 Af[4], Bf[2];
#pragma unroll
    for (int mt = 0; mt < 4; ++mt)
      Af[mt] = *(const frag8*)(&As[(mhalf + mt * 16 + l15) * 40 + quad * 8]);
#pragma unroll
    for (int nt = 0; nt < 2; ++nt)
      Bf[nt] = *(const frag8*)(&Bs[(nhalf + nt * 16 + l15) * 40 + quad * 8]);
#pragma unroll
    for (int mt = 0; mt < 4; ++mt)
#pragma unroll
      for (int nt = 0; nt < 2; ++nt)
        acc[mt][nt] = __builtin_amdgcn_mfma_f32_16x16x32_bf16(Af[mt], Bf[nt], acc[mt][nt], 0, 0, 0);
  }

#pragma unroll
  for (int mt = 0; mt < 4; ++mt)
#pragma unroll
    for (int nt = 0; nt < 2; ++nt)
#pragma unroll
      for (int reg = 0; reg < 4; ++reg) {
        int m = m0 + mhalf + mt * 16 + quad * 4 + reg;
        int n = n0 + nhalf + nt * 16 + l15;
        C[(size_t)m * DMODEL + n] = acc[mt][nt][reg];
      }
}

// ---------------------------------------------------------------------------
extern "C" void kernel_launch(void* const* d_in, const int* in_sizes, int n_in,
                              void* d_out, int out_size, void* d_ws, size_t ws_size,
                              hipStream_t stream) {
  const float* x    = (const float*)d_in[0];
  const float* pos  = (const float*)d_in[1];
  const float* Wm   = (const float*)d_in[2];
  const float* G    = (const float*)d_in[3];
  const float* Wout = (const float*)d_in[4];
  float* out = (float*)d_out;

  float* ws = (float*)d_ws;
  float* masses = ws;                                    // 65536 fp32
  float* invd = ws + 65536;                              // 4M fp32
  __hip_bfloat16* attnout = (__hip_bfloat16*)(invd + (size_t)SEQ * SEQ);  // 4M bf16

  masses_kernel<<<(BATCH * NHEAD * SEQ) / 256, 256, 0, stream>>>(x, Wm, masses);
  invdist_kernel<<<dim3(SEQ / 64, SEQ / 64), 256, 0, stream>>>(pos, invd);
  attn_mfma_kernel<<<dim3(BATCH * NHEAD, SEQ / 128), 256, 0, stream>>>(
      x, masses, invd, G, attnout);
  out_gemm_mfma<<<dim3(DMODEL / 64, (BATCH * SEQ) / 128), 256, 0, stream>>>(
      attnout, Wout, out);
}

// Round 5
// 207.256 us; speedup vs baseline: 10.2028x; 1.1483x over previous
//
#include <hip/hip_runtime.h>
#include <hip/hip_bf16.h>

#define SEQ 2048
#define DMODEL 1024
#define NHEAD 16
#define HDIM 64
#define DPOS 64
#define BATCH 2

constexpr float EVENT_HORIZON = 1e-6f;
constexpr float MAX_FORCE = 50.0f;
constexpr float CURV = 0.15f;

typedef __attribute__((ext_vector_type(8))) short frag8;    // 8 bf16 (A/B operand)
typedef __attribute__((ext_vector_type(4))) float frag4f;   // 4 fp32 (C/D)

__device__ inline short bfbits(float f) {
  __hip_bfloat16 h = __float2bfloat16(f);
  return *reinterpret_cast<short*>(&h);
}
__device__ inline float bf2f(unsigned short u) {
  unsigned v = ((unsigned)u) << 16;
  union { unsigned u; float f; } c; c.u = v; return c.f;
}

// ---------------------------------------------------------------------------
// Kernel 0: convert x -> xbf (bf16) and Wout -> Wbf (bf16), float4 at a time.
// ---------------------------------------------------------------------------
__global__ __launch_bounds__(256) void prep_bf16(
    const float* __restrict__ x, const float* __restrict__ Wout,
    unsigned short* __restrict__ xbf, unsigned short* __restrict__ wbf) {
  const int NX4 = (BATCH * SEQ * DMODEL) / 4;   // 1048576
  int i = blockIdx.x * 256 + threadIdx.x;
  float4 v;
  unsigned short* dst;
  if (i < NX4) {
    v = ((const float4*)x)[i];
    dst = xbf + 4 * (size_t)i;
  } else {
    int k = i - NX4;
    v = ((const float4*)Wout)[k];
    dst = wbf + 4 * (size_t)k;
  }
  ushort4 o;
  o.x = (unsigned short)bfbits(v.x); o.y = (unsigned short)bfbits(v.y);
  o.z = (unsigned short)bfbits(v.z); o.w = (unsigned short)bfbits(v.w);
  *(ushort4*)dst = o;
}

// ---------------------------------------------------------------------------
// Kernel 1: masses[bh][s] = softplus( dot(x[b,s,h*64:+64], W_mass[h,:]) )
// ---------------------------------------------------------------------------
__global__ __launch_bounds__(256) void masses_kernel(
    const float* __restrict__ x, const float* __restrict__ Wm,
    float* __restrict__ masses) {
  int n = blockIdx.x * blockDim.x + threadIdx.x;
  if (n >= BATCH * NHEAD * SEQ) return;
  int s  = n & (SEQ - 1);
  int bh = n >> 11;
  int h  = bh & (NHEAD - 1);
  int b  = bh >> 4;
  const float* xp = x + ((size_t)(b * SEQ + s)) * DMODEL + h * HDIM;
  const float* wp = Wm + h * HDIM;
  float acc = 0.f;
#pragma unroll
  for (int d = 0; d < HDIM; ++d) acc += xp[d] * wp[d];
  masses[n] = (acc > 20.f) ? acc : log1pf(expf(acc));
}

// ---------------------------------------------------------------------------
// Kernel 2: LDS-tiled distance kernel, bf16 output.
// invd_bf[i][j] = bf16( 1 / max( d2*(1+0.15*cos(sqrt(d2+eps))), eps ) )
// bf16 is safe: diagonal force clamps to exactly 50 (dist=0), dominating every
// row's softmax; off-diagonal weight <= e^(f-50) suppresses the 0.4% rel err.
// ---------------------------------------------------------------------------
__global__ __launch_bounds__(256) void invdist_kernel(
    const float* __restrict__ pos, unsigned short* __restrict__ invd) {
  __shared__ float Li[64 * 68];
  __shared__ float Lj[64 * 68];
  int t = threadIdx.x;
  int i0 = blockIdx.y * 64, j0 = blockIdx.x * 64;

  int kk = (t & 15) * 4;
  int rr = t >> 4;
#pragma unroll
  for (int q = 0; q < 4; ++q) {
    int row = q * 16 + rr;
    float4 a = *(const float4*)(pos + (size_t)(i0 + row) * DPOS + kk);
    float4 b = *(const float4*)(pos + (size_t)(j0 + row) * DPOS + kk);
    Li[(kk + 0) * 68 + row] = a.x; Li[(kk + 1) * 68 + row] = a.y;
    Li[(kk + 2) * 68 + row] = a.z; Li[(kk + 3) * 68 + row] = a.w;
    Lj[(kk + 0) * 68 + row] = b.x; Lj[(kk + 1) * 68 + row] = b.y;
    Lj[(kk + 2) * 68 + row] = b.z; Lj[(kk + 3) * 68 + row] = b.w;
  }
  __syncthreads();

  int ti = (t >> 4) * 4;
  int tj = (t & 15) * 4;

  float acc[4][4];
#pragma unroll
  for (int a = 0; a < 4; ++a)
#pragma unroll
    for (int b = 0; b < 4; ++b) acc[a][b] = 0.f;

#pragma unroll 8
  for (int k = 0; k < 64; ++k) {
    float4 a = *(const float4*)(&Li[k * 68 + ti]);
    float4 b = *(const float4*)(&Lj[k * 68 + tj]);
    float av[4] = {a.x, a.y, a.z, a.w};
    float bv[4] = {b.x, b.y, b.z, b.w};
#pragma unroll
    for (int mi = 0; mi < 4; ++mi)
#pragma unroll
      for (int mj = 0; mj < 4; ++mj) {
        float d = av[mi] - bv[mj];
        acc[mi][mj] += d * d;
      }
  }

#pragma unroll
  for (int mi = 0; mi < 4; ++mi) {
    ushort4 o;
    unsigned short* op = (unsigned short*)&o;
#pragma unroll
    for (int mj = 0; mj < 4; ++mj) {
      float d2 = acc[mi][mj];
      float dn = sqrtf(d2 + EVENT_HORIZON);
      float w = d2 * (1.f + CURV * __cosf(dn));
      op[mj] = (unsigned short)bfbits(1.0f / fmaxf(w, EVENT_HORIZON));
    }
    *(ushort4*)(&invd[(size_t)(i0 + ti + mi) * SEQ + j0 + tj]) = o;
  }
}

// ---------------------------------------------------------------------------
// Kernel 3: fused gravitational attention, MFMA PV.
// Block = 512 thr = 8 waves, covers (b, head-pair, 64 i-rows).
// Wave w: head = hp*2 + (w>>2), rows iw = i0 + (w&3)*16.
// Head-pairing: both heads' waves read the SAME invd rows -> L2 absorbs the
// second read (halves L3-side invd traffic). V staged bf16 from xbf.
// Scores in (0,50] -> softmax without max-subtraction safe in fp32.
// ---------------------------------------------------------------------------
__global__ __launch_bounds__(512, 4) void attn_mfma_kernel(
    const unsigned short* __restrict__ xbf, const float* __restrict__ masses,
    const unsigned short* __restrict__ invd, const float* __restrict__ G,
    __hip_bfloat16* __restrict__ attnout) {
  // Vt[hh][d][j]: stride 72 ushorts (144 B: 16B-aligned, bank-balanced)
  __shared__ unsigned short Vt[2 * 64 * 72];  // 18432 B

  int bp = blockIdx.x;           // b*8 + hpair
  int b = bp >> 3, hp = bp & 7;
  int i0 = blockIdx.y * 64;
  int t = threadIdx.x;
  int w = t >> 6, lane = t & 63;
  int l15 = lane & 15, quad = lane >> 4;
  int hh = w >> 2;               // head within pair (compute waves)
  int h = hp * 2 + hh;
  int bh = b * NHEAD + h;
  int iw = i0 + (w & 3) * 16;    // wave's first row

  float gabs = fabsf(G[h]);
  const float* mrow = masses + (size_t)bh * SEQ;
  float cm = gabs * mrow[iw + l15];                       // row scalar (m=l15)
  const unsigned short* ivrow = invd + (size_t)(iw + l15) * SEQ;

  // staging role: shh = t>>8 (head), sd = t&63 (dim), sjg = (t>>6)&3 (j-group)
  int shh = t >> 8, sd = t & 63, sjg = (t >> 6) & 3;
  const unsigned short* xcol =
      xbf + (size_t)b * SEQ * DMODEL + (hp * 2 + shh) * HDIM + sd;

  frag4f acc[4];
#pragma unroll
  for (int nt = 0; nt < 4; ++nt) acc[nt] = (frag4f)0.f;
  float sum = 0.f;

  for (int j0 = 0; j0 < SEQ; j0 += 64) {
    // ---- stage V chunk: 2 heads x 64j x 64d bf16 ----
    unsigned short vv[16];
#pragma unroll
    for (int jj = 0; jj < 16; ++jj)
      vv[jj] = xcol[(size_t)(j0 + sjg * 16 + jj) * DMODEL];
    __syncthreads();  // previous chunk's reads done
    {
      frag8 v0, v1;
#pragma unroll
      for (int jj = 0; jj < 8; ++jj) { v0[jj] = (short)vv[jj]; v1[jj] = (short)vv[8 + jj]; }
      *(frag8*)(&Vt[shh * 64 * 72 + sd * 72 + sjg * 16]) = v0;
      *(frag8*)(&Vt[shh * 64 * 72 + sd * 72 + sjg * 16 + 8]) = v1;
    }
    __syncthreads();  // writes visible

    // ---- two K-halves of 32 ----
#pragma unroll
    for (int kh = 0; kh < 2; ++kh) {
      int jb = j0 + kh * 32 + quad * 8;
      float4 m0 = *(const float4*)(mrow + jb);
      float4 m1 = *(const float4*)(mrow + jb + 4);
      float mj[8] = {m0.x, m0.y, m0.z, m0.w, m1.x, m1.y, m1.z, m1.w};
      frag8 ivv = *(const frag8*)(ivrow + jb);

      frag8 A;
#pragma unroll
      for (int jj = 0; jj < 8; ++jj) {
        float iv = bf2f((unsigned short)ivv[jj]);
        float e = __expf(fminf(cm * mj[jj] * iv, MAX_FORCE));
        short r = bfbits(e);
        sum += bf2f((unsigned short)r);
        A[jj] = r;
      }
#pragma unroll
      for (int nt = 0; nt < 4; ++nt) {
        frag8 Bf = *(const frag8*)(
            &Vt[hh * 64 * 72 + (nt * 16 + l15) * 72 + kh * 32 + quad * 8]);
        acc[nt] = __builtin_amdgcn_mfma_f32_16x16x32_bf16(A, Bf, acc[nt], 0, 0, 0);
      }
    }
  }

  // ---- normalize + store ----
  sum += __shfl_xor(sum, 16, 64);
  sum += __shfl_xor(sum, 32, 64);
  // lane L holds row-sum for row L&15

#pragma unroll
  for (int reg = 0; reg < 4; ++reg) {
    int r = quad * 4 + reg;          // C/D row within 16x16 tile
    float s = 1.f / __shfl(sum, r);
#pragma unroll
    for (int nt = 0; nt < 4; ++nt) {
      int dcol = h * HDIM + nt * 16 + l15;
      attnout[(size_t)(b * SEQ + iw + r) * DMODEL + dcol] =
          __float2bfloat16(acc[nt][reg] * s);
    }
  }
}

// ---------------------------------------------------------------------------
// Kernel 4: out = attnout @ Wbf^T via bf16 MFMA. C[m][n] = sum_k A[m][k]W[n][k]
// M=4096, N=K=1024. Tile 128(M) x 64(N), K-chunk 32. 4 waves, wave = 64m x 32n.
// ---------------------------------------------------------------------------
__global__ __launch_bounds__(256, 2) void out_gemm_mfma(
    const __hip_bfloat16* __restrict__ Ag, const unsigned short* __restrict__ Wg,
    float* __restrict__ C) {
  __shared__ __hip_bfloat16 As[128 * 40];
  __shared__ __hip_bfloat16 Bs[64 * 40];

  int t = threadIdx.x;
  int w = t >> 6, lane = t & 63;
  int l15 = lane & 15, quad = lane >> 4;
  int m0 = blockIdx.y * 128;
  int n0 = blockIdx.x * 64;
  int mhalf = (w & 1) * 64;
  int nhalf = (w >> 1) * 32;

  int ar = t >> 1, akb = t & 1;   // A: row 0..127, 16 bf16 each
  int br = t >> 2, bkb = t & 3;   // B: row 0..63, 8 bf16 each

  frag4f acc[4][2];
#pragma unroll
  for (int mt = 0; mt < 4; ++mt)
#pragma unroll
    for (int nt = 0; nt < 2; ++nt) acc[mt][nt] = (frag4f)0.f;

  for (int k0 = 0; k0 < DMODEL; k0 += 32) {
    const frag8* ap = (const frag8*)(Ag + (size_t)(m0 + ar) * DMODEL + k0 + akb * 16);
    frag8 a0 = ap[0], a1 = ap[1];
    frag8 bb = *(const frag8*)(Wg + (size_t)(n0 + br) * DMODEL + k0 + bkb * 8);

    __syncthreads();
    *(frag8*)(&As[ar * 40 + akb * 16]) = a0;
    *(frag8*)(&As[ar * 40 + akb * 16 + 8]) = a1;
    *(frag8*)(&Bs[br * 40 + bkb * 8]) = bb;
    __syncthreads();

    frag8 Af[4], Bf[2];
#pragma unroll
    for (int mt = 0; mt < 4; ++mt)
      Af[mt] = *(const frag8*)(&As[(mhalf + mt * 16 + l15) * 40 + quad * 8]);
#pragma unroll
    for (int nt = 0; nt < 2; ++nt)
      Bf[nt] = *(const frag8*)(&Bs[(nhalf + nt * 16 + l15) * 40 + quad * 8]);
#pragma unroll
    for (int mt = 0; mt < 4; ++mt)
#pragma unroll
      for (int nt = 0; nt < 2; ++nt)
        acc[mt][nt] = __builtin_amdgcn_mfma_f32_16x16x32_bf16(Af[mt], Bf[nt], acc[mt][nt], 0, 0, 0);
  }

#pragma unroll
  for (int mt = 0; mt < 4; ++mt)
#pragma unroll
    for (int nt = 0; nt < 2; ++nt)
#pragma unroll
      for (int reg = 0; reg < 4; ++reg) {
        int m = m0 + mhalf + mt * 16 + quad * 4 + reg;
        int n = n0 + nhalf + nt * 16 + l15;
        C[(size_t)m * DMODEL + n] = acc[mt][nt][reg];
      }
}

// ---------------------------------------------------------------------------
extern "C" void kernel_launch(void* const* d_in, const int* in_sizes, int n_in,
                              void* d_out, int out_size, void* d_ws, size_t ws_size,
                              hipStream_t stream) {
  const float* x    = (const float*)d_in[0];
  const float* pos  = (const float*)d_in[1];
  const float* Wm   = (const float*)d_in[2];
  const float* G    = (const float*)d_in[3];
  const float* Wout = (const float*)d_in[4];
  float* out = (float*)d_out;

  // workspace layout (bytes)
  char* wsb = (char*)d_ws;
  float* masses = (float*)wsb;                                   // 256 KB
  unsigned short* invd = (unsigned short*)(wsb + (1 << 18));     // 8 MB
  __hip_bfloat16* attnout = (__hip_bfloat16*)(wsb + (1 << 18) + (8 << 20));  // 8 MB
  unsigned short* xbf = (unsigned short*)(wsb + (1 << 18) + (16 << 20));     // 8 MB
  unsigned short* wbf = (unsigned short*)(wsb + (1 << 18) + (24 << 20));     // 2 MB

  const int NX4 = (BATCH * SEQ * DMODEL) / 4;
  const int NW4 = (DMODEL * DMODEL) / 4;
  prep_bf16<<<(NX4 + NW4) / 256, 256, 0, stream>>>(x, Wout, xbf, wbf);
  masses_kernel<<<(BATCH * NHEAD * SEQ) / 256, 256, 0, stream>>>(x, Wm, masses);
  invdist_kernel<<<dim3(SEQ / 64, SEQ / 64), 256, 0, stream>>>(pos, invd);
  attn_mfma_kernel<<<dim3(BATCH * (NHEAD / 2), SEQ / 64), 512, 0, stream>>>(
      xbf, masses, invd, G, attnout);
  out_gemm_mfma<<<dim3(DMODEL / 64, (BATCH * SEQ) / 128), 256, 0, stream>>>(
      attnout, wbf, out);
}